// Round 6
// baseline (176.669 us; speedup 1.0000x reference)
//
#include <hip/hip_runtime.h>

// ---------------------------------------------------------------------------
// Attention_25151328485403 — f16 MFMA path, round 15
//   prep:  converts (x->f16; W_qkv -> [N][K] q-cols ×0.125*log2e; W_out) +
//          per-batch masked-key counts
//   g1  :  qkv = x_h @ Wqkv^T, ALL rows ×mask[row] (exact 0/1); q,k -> qk
//          compact [row][2048]; V -> vt transposed [bh][64][2048], keys
//          permuted within 32-key blocks so V b128 chunk == PV A-slot order.
//   at  :  R11 inner structure, but 16 q/wave (128 q/block), grid 1024 =
//          4 blocks/CU = 32 waves/CU = 8 waves/SIMD (launch_bounds(512,8)),
//          XCD-aware block decode: each XCD owns 8 (bh,kh) pairs -> K/V
//          working set 2 MB fits per-XCD L2. P in-register; l via MFMA×ones.
//   g2  :  MODE 3 — fused combine+GEMM: A-staging computes
//          (O0+O1)[row][k] * inv[row][h(k)]; out = aout @ Wout^T (fp32).
// Lessons: R9/R10 Ps round-trip was the serial chain. R12 vmcnt ring NEUTRAL.
// R13 128-key attn + 1-block/CU gemm2 REGRESSED. R14 combine fused into g2.
// R15 theory: attn MfmaUtil 27% == 4 waves/SIMD x 36 MFMA x 19cy / 6600cy —
// occupancy-starved; double waves/CU, halve per-wave chain.
// ---------------------------------------------------------------------------

typedef _Float16 half_t;
typedef __attribute__((ext_vector_type(8))) _Float16 half8;
typedef __attribute__((ext_vector_type(4))) _Float16 half4;
typedef __attribute__((ext_vector_type(4))) float floatx4;

#define SEQ 2048
#define DIM 1024
#define INNER 1024
#define NH 16
#define DH 64
#define BROWS 4096

__device__ inline void async16(const half_t* g, half_t* l) {
    __builtin_amdgcn_global_load_lds(
        (const __attribute__((address_space(1))) void*)g,
        (__attribute__((address_space(3))) void*)l, 16, 0, 0);
}

// ------------------- fused prep (converts + mask counts) -------------------
__global__ __launch_bounds__(256) void prep(const float* __restrict__ x,
                                            const float* __restrict__ Wqkv,
                                            const float* __restrict__ Wout,
                                            const float* __restrict__ mask,
                                            half_t* __restrict__ x_h,
                                            half_t* __restrict__ Wqkv_t,
                                            half_t* __restrict__ Wout_t,
                                            float* __restrict__ mc) {
    __shared__ float tile[32][33];
    const int bid = blockIdx.x;
    const int tid = threadIdx.x;

    if (bid < 2048) {
        int i = (bid * 256 + tid) * 8;
        float4 v0 = *(const float4*)(x + i);
        float4 v1 = *(const float4*)(x + i + 4);
        half_t h[8];
        h[0] = (half_t)v0.x; h[1] = (half_t)v0.y; h[2] = (half_t)v0.z; h[3] = (half_t)v0.w;
        h[4] = (half_t)v1.x; h[5] = (half_t)v1.y; h[6] = (half_t)v1.z; h[7] = (half_t)v1.w;
        *(half8*)(x_h + i) = *(half8*)h;
        return;
    }
    if (bid >= 6144) {                        // masked-key count for batch b
        int b = bid - 6144;
        float4 a = ((const float4*)(mask + (size_t)b * SEQ))[tid * 2];
        float4 c = ((const float4*)(mask + (size_t)b * SEQ))[tid * 2 + 1];
        float s = a.x + a.y + a.z + a.w + c.x + c.y + c.z + c.w;
#pragma unroll
        for (int off = 1; off < 64; off <<= 1) s += __shfl_xor(s, off, 64);
        float* red = &tile[0][0];
        if ((tid & 63) == 0) red[tid >> 6] = s;
        __syncthreads();
        if (tid == 0) mc[b] = (float)SEQ - (red[0] + red[1] + red[2] + red[3]);
        return;
    }

    const float* in;
    half_t* out;
    int R, C, scaleRows, c0, r0;
    float scale;
    if (bid < 5120) {
        int idx = bid - 2048;                 // W_qkv: 96 x 32 tiles
        in = Wqkv; out = Wqkv_t; R = DIM; C = 3 * INNER;
        scaleRows = INNER; scale = 0.1803368801111f;   // 0.125 * log2(e)
        c0 = (idx % 96) * 32; r0 = (idx / 96) * 32;
    } else {
        int idx = bid - 5120;                 // W_out: 32 x 32 tiles
        in = Wout; out = Wout_t; R = INNER; C = DIM;
        scaleRows = 0; scale = 1.0f;
        c0 = (idx % 32) * 32; r0 = (idx / 32) * 32;
    }
    const int tx = tid & 31, ty = tid >> 5;
#pragma unroll
    for (int i = 0; i < 32; i += 8)
        tile[ty + i][tx] = in[(size_t)(r0 + ty + i) * C + c0 + tx];
    __syncthreads();
#pragma unroll
    for (int i = 0; i < 32; i += 8) {
        int oc = c0 + ty + i;
        float s = (oc < scaleRows) ? scale : 1.0f;
        out[(size_t)oc * R + r0 + tx] = (half_t)(tile[tx][ty + i] * s);
    }
}

// ------------------------------ mfma GEMM ----------------------------------
// MODE 0: f32 C[M,N].
// MODE 2: qkv — rows scaled by mask[row]; cols<2048 -> qk [row][2048] f16;
//         cols>=2048 -> vt [bh][64 d][2048 seq-permuted].
// MODE 3: fused combine+GEMM: A-staging = (A + A1)[row][k] * inv[row][h],
//         h = k/64; inv from lws (l0+l1-mc) and q-mask, built in LDS.
template <int MODE, int WMT, int WNT>
__global__ __launch_bounds__(256) void gemm_f16_bt(const half_t* __restrict__ A,
                                                   const half_t* __restrict__ B,
                                                   void* __restrict__ Cout,
                                                   half_t* __restrict__ vt,
                                                   const float* __restrict__ mask,
                                                   const float* __restrict__ lws,
                                                   int M, int N, int K) {
    constexpr int BM = 32 * WMT;
    constexpr int BN = 32 * WNT;
    __shared__ half_t As[BM * 64];
    __shared__ half_t Bs[BN * 64];
    const int tid = threadIdx.x;
    const int wave = tid >> 6;
    const int lane = tid & 63;
    const int l15 = lane & 15;
    const int quad = lane >> 4;
    const int m0 = blockIdx.y * BM;
    const int n0 = blockIdx.x * BN;
    const int wm = (wave & 1) * (16 * WMT);
    const int wn = (wave >> 1) * (16 * WNT);

    floatx4 acc[WMT][WNT];
#pragma unroll
    for (int i = 0; i < WMT; ++i)
#pragma unroll
        for (int j = 0; j < WNT; ++j) acc[i][j] = (floatx4){0.f, 0.f, 0.f, 0.f};

    if constexpr (MODE == 3) {
        static_assert(WMT == 2, "MODE 3 assumes BM=64");
        const half_t* A1 = vt;            // second input (O1)
        __shared__ float invL[64][16];
        // ---- build inv table: inv[row][h] = qmask / (l0+l1-mc) ----
        {
            int r = tid >> 2;
            int rg = m0 + r;
            int bb = rg >> 11;
            int q = rg & 2047;
            float qm = mask[rg];
            float mcv = lws[131072 + bb];
#pragma unroll
            for (int j = 0; j < 4; ++j) {
                int it = (tid & 3) * 4 + j;
                float l0 = lws[(size_t)(bb * 16 + it) * 2048 + q];
                float l1 = lws[65536 + (size_t)(bb * 16 + it) * 2048 + q];
                float l = l0 + l1 - mcv;
                invL[r][it] = (qm > 0.5f && l > 0.f) ? 1.0f / l : 0.f;
            }
        }
        // ---- preload A regs for kit 0 ----
        const int ch0 = tid, ch1 = 256 + tid;
        const int r0 = ch0 >> 3, g0 = (ch0 & 7) ^ (r0 & 7);
        const int r1 = ch1 >> 3, g1 = (ch1 & 7) ^ (r1 & 7);
        const half_t* a0p = A + (size_t)(m0 + r0) * K + g0 * 8;
        const half_t* b0p = A1 + (size_t)(m0 + r0) * K + g0 * 8;
        const half_t* a1p = A + (size_t)(m0 + r1) * K + g1 * 8;
        const half_t* b1p = A1 + (size_t)(m0 + r1) * K + g1 * 8;
        half8 aC0 = *(const half8*)(a0p);
        half8 bC0 = *(const half8*)(b0p);
        half8 aC1 = *(const half8*)(a1p);
        half8 bC1 = *(const half8*)(b1p);

        for (int kit = 0; kit < 16; ++kit) {
            const int k0 = kit * 64;
            __syncthreads();              // prev compute done; As/Bs free
            // combined, scaled A -> LDS
            {
                float iv0 = invL[r0][kit], iv1 = invL[r1][kit];
                half8 s0, s1;
#pragma unroll
                for (int j = 0; j < 8; ++j) {
                    s0[j] = (half_t)(((float)aC0[j] + (float)bC0[j]) * iv0);
                    s1[j] = (half_t)(((float)aC1[j] + (float)bC1[j]) * iv1);
                }
                *(half8*)(As + ch0 * 8) = s0;
                *(half8*)(As + ch1 * 8) = s1;
            }
            // B staging via global_load_lds
#pragma unroll
            for (int i = 0; i < BN * 8 / 256; ++i) {
                int chunk = i * 256 + tid;
                int row = chunk >> 3, c = chunk & 7;
                int gc = c ^ (row & 7);
                async16(B + (size_t)(n0 + row) * K + k0 + gc * 8, Bs + chunk * 8);
            }
            // prefetch next-iteration A regs (rides the barrier's B drain)
            if (kit + 1 < 16) {
                const int kn = k0 + 64;
                aC0 = *(const half8*)(a0p + kn);
                bC0 = *(const half8*)(b0p + kn);
                aC1 = *(const half8*)(a1p + kn);
                bC1 = *(const half8*)(b1p + kn);
            }
            __syncthreads();              // staging (LDS + vmem) drained
#pragma unroll
            for (int ks = 0; ks < 2; ++ks) {
                const int g = ks * 4 + quad;
                half8 af[WMT], bf[WNT];
#pragma unroll
                for (int i = 0; i < WMT; ++i) {
                    int m = wm + i * 16 + l15;
                    af[i] = *(const half8*)(As + m * 64 + (g ^ (m & 7)) * 8);
                }
#pragma unroll
                for (int j = 0; j < WNT; ++j) {
                    int n = wn + j * 16 + l15;
                    bf[j] = *(const half8*)(Bs + n * 64 + (g ^ (n & 7)) * 8);
                }
#pragma unroll
                for (int i = 0; i < WMT; ++i)
#pragma unroll
                    for (int j = 0; j < WNT; ++j)
                        acc[i][j] = __builtin_amdgcn_mfma_f32_16x16x32_f16(
                            af[i], bf[j], acc[i][j], 0, 0, 0);
            }
        }
#pragma unroll
        for (int i = 0; i < WMT; ++i)
#pragma unroll
            for (int j = 0; j < WNT; ++j)
#pragma unroll
                for (int r = 0; r < 4; ++r) {
                    size_t row = m0 + wm + i * 16 + quad * 4 + r;
                    size_t col = n0 + wn + j * 16 + l15;
                    ((float*)Cout)[row * N + col] = acc[i][j][r];
                }
        return;
    }

    for (int k0 = 0; k0 < K; k0 += 64) {
        __syncthreads();
#pragma unroll
        for (int i = 0; i < BM * 8 / 256; ++i) {
            int chunk = i * 256 + tid;
            int row = chunk >> 3, c = chunk & 7;
            int gc = c ^ (row & 7);
            async16(A + (size_t)(m0 + row) * K + k0 + gc * 8, As + chunk * 8);
        }
#pragma unroll
        for (int i = 0; i < BN * 8 / 256; ++i) {
            int chunk = i * 256 + tid;
            int row = chunk >> 3, c = chunk & 7;
            int gc = c ^ (row & 7);
            async16(B + (size_t)(n0 + row) * K + k0 + gc * 8, Bs + chunk * 8);
        }
        __syncthreads();
#pragma unroll
        for (int ks = 0; ks < 2; ++ks) {
            const int g = ks * 4 + quad;
            half8 af[WMT], bf[WNT];
#pragma unroll
            for (int i = 0; i < WMT; ++i) {
                int m = wm + i * 16 + l15;
                af[i] = *(const half8*)(As + m * 64 + (g ^ (m & 7)) * 8);
            }
#pragma unroll
            for (int j = 0; j < WNT; ++j) {
                int n = wn + j * 16 + l15;
                bf[j] = *(const half8*)(Bs + n * 64 + (g ^ (n & 7)) * 8);
            }
#pragma unroll
            for (int i = 0; i < WMT; ++i)
#pragma unroll
                for (int j = 0; j < WNT; ++j)
                    acc[i][j] = __builtin_amdgcn_mfma_f32_16x16x32_f16(af[i], bf[j],
                                                                       acc[i][j], 0, 0, 0);
        }
    }

    if (MODE == 2) {
        // scale all rows by mask (exact 0/1): masked K -> s=0, masked V -> 0
#pragma unroll
        for (int i = 0; i < WMT; ++i) {
            int row0 = m0 + wm + i * 16 + quad * 4;
            float4 mv = *(const float4*)(mask + row0);
            float mvr[4] = {mv.x, mv.y, mv.z, mv.w};
            if (n0 >= 2 * INNER) {            // V block -> vt transposed
                int seq0 = row0 & (SEQ - 1);
                // permute 4-key groups within each 32-key block:
                // g = mtl*4 + q  ->  g' = q*2 + mtl, so a contiguous b128
                // chunk in vt is exactly the PV A-fragment slot order.
                int g = (seq0 >> 2) & 7;
                int seqp = (seq0 & ~31) | ((((g & 3) << 1) | (g >> 2)) << 2);
                int bhb = (row0 >> 11) << 4;
#pragma unroll
                for (int j = 0; j < WNT; ++j) {
                    int vc = n0 + wn + j * 16 + l15 - 2 * INNER;
                    half4 v4;
#pragma unroll
                    for (int r = 0; r < 4; ++r) v4[r] = (half_t)(acc[i][j][r] * mvr[r]);
                    *(half4*)(vt + ((size_t)(bhb + (vc >> 6)) * DH + (vc & 63)) * SEQ +
                              seqp) = v4;
                }
            } else {                          // q/k block -> compact qk
#pragma unroll
                for (int j = 0; j < WNT; ++j) {
                    size_t col = n0 + wn + j * 16 + l15;
#pragma unroll
                    for (int r = 0; r < 4; ++r)
                        ((half_t*)Cout)[(size_t)(row0 + r) * 2048 + col] =
                            (half_t)(acc[i][j][r] * mvr[r]);
                }
            }
        }
        return;
    }

#pragma unroll
    for (int i = 0; i < WMT; ++i)
#pragma unroll
        for (int j = 0; j < WNT; ++j)
#pragma unroll
            for (int r = 0; r < 4; ++r) {
                size_t row = m0 + wm + i * 16 + quad * 4 + r;
                size_t col = n0 + wn + j * 16 + l15;
                ((float*)Cout)[row * N + col] = acc[i][j][r];
            }
}

// ------------------------------ attention ----------------------------------
// 512 thr = 8 waves; 16 q/wave (128 q/block); grid 1024 blocks = 4 blocks/CU
// = 32 waves/CU = 8 waves/SIMD. XCD-aware decode: lin -> (xcd = lin&7,
// slot = lin>>3), w = xcd*128+slot; each XCD owns 8 contiguous (bh,kh)
// pairs -> K/V working set 2 MB fits per-XCD L2. Inner structure = R11:
// 64-key double-buffered tiles (32 KB LDS), one __syncthreads per tile,
// P in-register (vt key permutation), l via MFMA×ones.
__global__ __launch_bounds__(512, 8) void attn_mfma(const half_t* __restrict__ qk,
                                                    const half_t* __restrict__ vt,
                                                    half_t* __restrict__ O0,
                                                    half_t* __restrict__ O1,
                                                    float* __restrict__ l_ws) {
    __shared__ half_t Ks[2][64 * 64];     // [key][d], chunks xor-swizzled (16 KB)
    __shared__ half_t Vs[2][64 * 64];     // [d][key-perm], xor-swizzled  (16 KB)

    const int tid = threadIdx.x;
    const int wave = tid >> 6;
    const int lane = tid & 63;
    const int l15 = lane & 15;
    const int quad = lane >> 4;
    const int sw = l15 & 7;

    // XCD-aware work decode (bijective on [0,1024))
    const int lin = blockIdx.x;
    const int w = (lin & 7) * 128 + (lin >> 3);
    const int pairid = w >> 4;            // [0,64): 4 bh x 2 kh per XCD-octant
    const int qib = w & 15;
    const int bh = pairid >> 1;
    const int kh = pairid & 1;            // keys [kh*1024, kh*1024+1024)
    const int b = bh >> 4, h = bh & 15;
    const int qi0 = qib * 128;

    // Q fragments from global (0.125*log2e folded into W_qkv q-cols)
    const half_t* qrow0 = qk + (size_t)(b * SEQ + qi0 + wave * 16 + l15) * 2048 + h * DH;
    half8 qf[2];
    qf[0] = *(const half8*)(qrow0 + quad * 8);
    qf[1] = *(const half8*)(qrow0 + 32 + quad * 8);

    const half_t* kbase0 = qk + (size_t)b * SEQ * 2048 + INNER + h * DH;
    const half_t* vtb = vt + (size_t)bh * DH * SEQ;

    half8 vone;                           // B = 1 fragment for l-MFMA
#pragma unroll
    for (int j = 0; j < 8; ++j) vone[j] = (half_t)1.0f;

    floatx4 accO[4];
#pragma unroll
    for (int nt = 0; nt < 4; ++nt) accO[nt] = (floatx4){0.f, 0.f, 0.f, 0.f};
    floatx4 accL = (floatx4){0.f, 0.f, 0.f, 0.f};

    auto stage = [&](int kt, int buf) {
        const int kjg = kh * 1024 + kt * 64;
        int row = tid >> 3, c = tid & 7;
        int gc = c ^ (row & 7);
        async16(kbase0 + (size_t)(kjg + row) * 2048 + gc * 8, Ks[buf] + tid * 8);
        async16(vtb + (size_t)row * SEQ + kjg + gc * 8, Vs[buf] + tid * 8);
    };

    stage(0, 0);

    for (int kt = 0; kt < 16; ++kt) {
        const int buf = kt & 1;
        __syncthreads();                  // buf's loads drained; buf^1 reads done
        if (kt + 1 < 16) stage(kt + 1, buf ^ 1);   // ages a full tile

        // ---- S^T = K Q^T : rows = keys (mt*16+quad*4+r), cols = q (l15) ----
        floatx4 accS[4];
#pragma unroll
        for (int mt = 0; mt < 4; ++mt) accS[mt] = (floatx4){0.f, 0.f, 0.f, 0.f};
        __builtin_amdgcn_s_setprio(1);
#pragma unroll
        for (int ks = 0; ks < 2; ++ks) {
#pragma unroll
            for (int mt = 0; mt < 4; ++mt) {
                half8 af = *(const half8*)(Ks[buf] + (mt * 16 + l15) * 64 +
                                           ((ks * 4 + quad) ^ sw) * 8);
                accS[mt] = __builtin_amdgcn_mfma_f32_16x16x32_f16(af, qf[ks],
                                                                  accS[mt], 0, 0, 0);
            }
        }
        __builtin_amdgcn_s_setprio(0);

        // ---- p = 2^s, packed in-register as the PV A-fragment ----
        half8 pf[2];                      // [c]: keys c*32 + quad*8 + j
#pragma unroll
        for (int c = 0; c < 2; ++c) {
            half8 p8;
#pragma unroll
            for (int mtl = 0; mtl < 2; ++mtl)
#pragma unroll
                for (int r = 0; r < 4; ++r)
                    p8[mtl * 4 + r] =
                        (half_t)__builtin_amdgcn_exp2f(accS[c * 2 + mtl][r]);
            pf[c] = p8;
        }

        // ---- PV + l: vf b128 chunk == A-slot key order (vt pre-permuted) ----
        __builtin_amdgcn_s_setprio(1);
#pragma unroll
        for (int c = 0; c < 2; ++c) {
            const int ko = ((c * 4 + quad) ^ sw) * 8;
            accL = __builtin_amdgcn_mfma_f32_16x16x32_f16(pf[c], vone, accL, 0, 0, 0);
#pragma unroll
            for (int nt = 0; nt < 4; ++nt) {
                half8 vf = *(const half8*)(Vs[buf] + (nt * 16 + l15) * 64 + ko);
                accO[nt] = __builtin_amdgcn_mfma_f32_16x16x32_f16(pf[c], vf,
                                                                  accO[nt], 0, 0, 0);
            }
        }
        __builtin_amdgcn_s_setprio(0);
    }

    // l: accL[r] = Sum_k p for q = wave*16 + quad*4 + r (all l15 identical)
    float* lw = l_ws + (size_t)kh * 65536 + (size_t)bh * SEQ + qi0 + wave * 16;
    if (l15 == 0) {
#pragma unroll
        for (int r = 0; r < 4; ++r)
            lw[quad * 4 + r] = accL[r];
    }

    half_t* obuf = (kh == 0) ? O0 : O1;
#pragma unroll
    for (int nt = 0; nt < 4; ++nt)
#pragma unroll
        for (int r = 0; r < 4; ++r) {
            size_t row = (size_t)(b * SEQ + qi0 + wave * 16 + quad * 4 + r);
            obuf[row * INNER + h * DH + nt * 16 + l15] = (half_t)accO[nt][r];
        }
}

// ------------------------------- launch ------------------------------------
extern "C" void kernel_launch(void* const* d_in, const int* in_sizes, int n_in,
                              void* d_out, int out_size, void* d_ws, size_t ws_size,
                              hipStream_t stream) {
    const float* x    = (const float*)d_in[0];
    const float* mask = (const float*)d_in[1];
    const float* Wqkv = (const float*)d_in[2];   // [1024][3072]
    const float* Wout = (const float*)d_in[3];   // [1024][1024]
    float* out = (float*)d_out;

    half_t* x_h    = (half_t*)d_ws;                       // also O0 after g1
    half_t* Wqkv_t = x_h + (size_t)4 * 1024 * 1024;
    half_t* Wout_t = Wqkv_t + (size_t)3 * 1024 * 1024;
    half_t* qk     = Wout_t + (size_t)1024 * 1024;        // [4096][2048]
    half_t* vt     = qk + (size_t)8 * 1024 * 1024;        // [32][64][2048]
    half_t* aout_h = vt + (size_t)4 * 1024 * 1024;        // [4096][1024] = O1
    float*  l_ws   = (float*)(aout_h + (size_t)4 * 1024 * 1024);  // 2*65536 + 2
    half_t* O0     = x_h;

    prep<<<6146, 256, 0, stream>>>(x, Wqkv, Wout, mask, x_h, Wqkv_t, Wout_t,
                                   l_ws + 131072);

    gemm_f16_bt<2, 4, 4><<<dim3(3 * INNER / 128, BROWS / 128), 256, 0, stream>>>(
        x_h, Wqkv_t, qk, vt, mask, nullptr, BROWS, 3 * INNER, DIM);

    attn_mfma<<<dim3(1024), 512, 0, stream>>>(qk, vt, O0, aout_h, l_ws);

    // fused combine+GEMM: A = (O0 + O1) * inv, out = A @ Wout^T
    gemm_f16_bt<3, 2, 4><<<dim3(DIM / 128, BROWS / 64), 256, 0, stream>>>(
        O0, Wout_t, out, aout_h, mask, l_ws, BROWS, DIM, INNER);
}

// Round 7
// 172.412 us; speedup vs baseline: 1.0247x; 1.0247x over previous
//
#include <hip/hip_runtime.h>

// ---------------------------------------------------------------------------
// Attention_25151328485403 — f16 MFMA path, round 16
//   prep:  converts (x->f16; W_qkv -> [N][K] q-cols ×0.125*log2e; W_out) +
//          per-batch masked-key counts
//   g1  :  qkv = x_h @ Wqkv^T, rows ×mask[row]; q,k -> qk [row][2048];
//          V -> vt [bh][64 d][2048 seq-permuted]. NEW: epilogue stages the
//          128x128 block output in LDS (permute applied on LDS write) and
//          streams out coalesced b128 rows — kills the 8B vt scatter and
//          32B qk segments. XCD-aware block swizzle.
//   at  :  R11 structure verbatim (proven best: 8 waves, 256 q/block, 2-way
//          key split, 64-key dbuf tiles, P in-register, l via MFMA×ones).
//   g2  :  MODE 3 fused combine+GEMM (A = (O0+O1)*inv), XCD swizzle.
// Lessons: R9/R10 Ps LDS round-trip was the serial chain. R12 vmcnt ring
// NEUTRAL. R13 128-key attn + 1-block/CU gemm2 REGRESSED. R14 combine fused.
// R15 16q/wave REGRESSED (2x staging traffic, half intensity) -> attn local
// optimum = R11. R16: g1 epilogue was an HBM scatter -> LDS-transpose stores.
// ---------------------------------------------------------------------------

typedef _Float16 half_t;
typedef __attribute__((ext_vector_type(8))) _Float16 half8;
typedef __attribute__((ext_vector_type(4))) _Float16 half4;
typedef __attribute__((ext_vector_type(4))) float floatx4;

#define SEQ 2048
#define DIM 1024
#define INNER 1024
#define NH 16
#define DH 64
#define BROWS 4096

__device__ inline void async16(const half_t* g, half_t* l) {
    __builtin_amdgcn_global_load_lds(
        (const __attribute__((address_space(1))) void*)g,
        (__attribute__((address_space(3))) void*)l, 16, 0, 0);
}

// ------------------- fused prep (converts + mask counts) -------------------
__global__ __launch_bounds__(256) void prep(const float* __restrict__ x,
                                            const float* __restrict__ Wqkv,
                                            const float* __restrict__ Wout,
                                            const float* __restrict__ mask,
                                            half_t* __restrict__ x_h,
                                            half_t* __restrict__ Wqkv_t,
                                            half_t* __restrict__ Wout_t,
                                            float* __restrict__ mc) {
    __shared__ float tile[32][33];
    const int bid = blockIdx.x;
    const int tid = threadIdx.x;

    if (bid < 2048) {
        int i = (bid * 256 + tid) * 8;
        float4 v0 = *(const float4*)(x + i);
        float4 v1 = *(const float4*)(x + i + 4);
        half_t h[8];
        h[0] = (half_t)v0.x; h[1] = (half_t)v0.y; h[2] = (half_t)v0.z; h[3] = (half_t)v0.w;
        h[4] = (half_t)v1.x; h[5] = (half_t)v1.y; h[6] = (half_t)v1.z; h[7] = (half_t)v1.w;
        *(half8*)(x_h + i) = *(half8*)h;
        return;
    }
    if (bid >= 6144) {                        // masked-key count for batch b
        int b = bid - 6144;
        float4 a = ((const float4*)(mask + (size_t)b * SEQ))[tid * 2];
        float4 c = ((const float4*)(mask + (size_t)b * SEQ))[tid * 2 + 1];
        float s = a.x + a.y + a.z + a.w + c.x + c.y + c.z + c.w;
#pragma unroll
        for (int off = 1; off < 64; off <<= 1) s += __shfl_xor(s, off, 64);
        float* red = &tile[0][0];
        if ((tid & 63) == 0) red[tid >> 6] = s;
        __syncthreads();
        if (tid == 0) mc[b] = (float)SEQ - (red[0] + red[1] + red[2] + red[3]);
        return;
    }

    const float* in;
    half_t* out;
    int R, C, scaleRows, c0, r0;
    float scale;
    if (bid < 5120) {
        int idx = bid - 2048;                 // W_qkv: 96 x 32 tiles
        in = Wqkv; out = Wqkv_t; R = DIM; C = 3 * INNER;
        scaleRows = INNER; scale = 0.1803368801111f;   // 0.125 * log2(e)
        c0 = (idx % 96) * 32; r0 = (idx / 96) * 32;
    } else {
        int idx = bid - 5120;                 // W_out: 32 x 32 tiles
        in = Wout; out = Wout_t; R = INNER; C = DIM;
        scaleRows = 0; scale = 1.0f;
        c0 = (idx % 32) * 32; r0 = (idx / 32) * 32;
    }
    const int tx = tid & 31, ty = tid >> 5;
#pragma unroll
    for (int i = 0; i < 32; i += 8)
        tile[ty + i][tx] = in[(size_t)(r0 + ty + i) * C + c0 + tx];
    __syncthreads();
#pragma unroll
    for (int i = 0; i < 32; i += 8) {
        int oc = c0 + ty + i;
        float s = (oc < scaleRows) ? scale : 1.0f;
        out[(size_t)oc * R + r0 + tx] = (half_t)(tile[tx][ty + i] * s);
    }
}

// ------------------------------ mfma GEMM ----------------------------------
// MODE 0: f32 C[M,N].
// MODE 2: qkv — rows scaled by mask[row]; q/k -> qk [row][2048] f16 and
//         V -> vt [bh][64][2048 perm], both via LDS-staged coalesced stores.
// MODE 3: fused combine+GEMM: A-staging = (A + A1)[row][k] * inv[row][h].
// All modes: XCD-aware block swizzle (8 | gridDim.x*gridDim.y).
template <int MODE, int WMT, int WNT>
__global__ __launch_bounds__(256) void gemm_f16_bt(const half_t* __restrict__ A,
                                                   const half_t* __restrict__ B,
                                                   void* __restrict__ Cout,
                                                   half_t* __restrict__ vt,
                                                   const float* __restrict__ mask,
                                                   const float* __restrict__ lws,
                                                   int M, int N, int K) {
    constexpr int BM = 32 * WMT;
    constexpr int BN = 32 * WNT;
    constexpr int ABSZ = BM * 64 + BN * 64;
    constexpr int SHSZ = (MODE == 2 && ABSZ < 128 * 136) ? 128 * 136 : ABSZ;
    __shared__ half_t Sh[SHSZ];
    half_t* As = Sh;
    half_t* Bs = Sh + BM * 64;
    const int tid = threadIdx.x;
    const int wave = tid >> 6;
    const int lane = tid & 63;
    const int l15 = lane & 15;
    const int quad = lane >> 4;

    // XCD-aware swizzle: consecutive zz within an XCD share A-panels.
    const int z = blockIdx.y * gridDim.x + blockIdx.x;
    const int tot = gridDim.x * gridDim.y;
    const int zz = (z & 7) * (tot >> 3) + (z >> 3);
    const int m0 = (zz / gridDim.x) * BM;
    const int n0 = (zz % gridDim.x) * BN;
    const int wm = (wave & 1) * (16 * WMT);
    const int wn = (wave >> 1) * (16 * WNT);

    floatx4 acc[WMT][WNT];
#pragma unroll
    for (int i = 0; i < WMT; ++i)
#pragma unroll
        for (int j = 0; j < WNT; ++j) acc[i][j] = (floatx4){0.f, 0.f, 0.f, 0.f};

    if constexpr (MODE == 3) {
        static_assert(WMT == 2, "MODE 3 assumes BM=64");
        const half_t* A1 = vt;            // second input (O1)
        __shared__ float invL[64][16];
        // ---- build inv table: inv[row][h] = qmask / (l0+l1-mc) ----
        {
            int r = tid >> 2;
            int rg = m0 + r;
            int bb = rg >> 11;
            int q = rg & 2047;
            float qm = mask[rg];
            float mcv = lws[131072 + bb];
#pragma unroll
            for (int j = 0; j < 4; ++j) {
                int it = (tid & 3) * 4 + j;
                float l0 = lws[(size_t)(bb * 16 + it) * 2048 + q];
                float l1 = lws[65536 + (size_t)(bb * 16 + it) * 2048 + q];
                float l = l0 + l1 - mcv;
                invL[r][it] = (qm > 0.5f && l > 0.f) ? 1.0f / l : 0.f;
            }
        }
        // ---- preload A regs for kit 0 ----
        const int ch0 = tid, ch1 = 256 + tid;
        const int r0 = ch0 >> 3, g0 = (ch0 & 7) ^ (r0 & 7);
        const int r1 = ch1 >> 3, g1 = (ch1 & 7) ^ (r1 & 7);
        const half_t* a0p = A + (size_t)(m0 + r0) * K + g0 * 8;
        const half_t* b0p = A1 + (size_t)(m0 + r0) * K + g0 * 8;
        const half_t* a1p = A + (size_t)(m0 + r1) * K + g1 * 8;
        const half_t* b1p = A1 + (size_t)(m0 + r1) * K + g1 * 8;
        half8 aC0 = *(const half8*)(a0p);
        half8 bC0 = *(const half8*)(b0p);
        half8 aC1 = *(const half8*)(a1p);
        half8 bC1 = *(const half8*)(b1p);

        for (int kit = 0; kit < 16; ++kit) {
            const int k0 = kit * 64;
            __syncthreads();              // prev compute done; As/Bs free
            // combined, scaled A -> LDS
            {
                float iv0 = invL[r0][kit], iv1 = invL[r1][kit];
                half8 s0, s1;
#pragma unroll
                for (int j = 0; j < 8; ++j) {
                    s0[j] = (half_t)(((float)aC0[j] + (float)bC0[j]) * iv0);
                    s1[j] = (half_t)(((float)aC1[j] + (float)bC1[j]) * iv1);
                }
                *(half8*)(As + ch0 * 8) = s0;
                *(half8*)(As + ch1 * 8) = s1;
            }
            // B staging via global_load_lds
#pragma unroll
            for (int i = 0; i < BN * 8 / 256; ++i) {
                int chunk = i * 256 + tid;
                int row = chunk >> 3, c = chunk & 7;
                int gc = c ^ (row & 7);
                async16(B + (size_t)(n0 + row) * K + k0 + gc * 8, Bs + chunk * 8);
            }
            // prefetch next-iteration A regs (rides the barrier's B drain)
            if (kit + 1 < 16) {
                const int kn = k0 + 64;
                aC0 = *(const half8*)(a0p + kn);
                bC0 = *(const half8*)(b0p + kn);
                aC1 = *(const half8*)(a1p + kn);
                bC1 = *(const half8*)(b1p + kn);
            }
            __syncthreads();              // staging (LDS + vmem) drained
#pragma unroll
            for (int ks = 0; ks < 2; ++ks) {
                const int g = ks * 4 + quad;
                half8 af[WMT], bf[WNT];
#pragma unroll
                for (int i = 0; i < WMT; ++i) {
                    int m = wm + i * 16 + l15;
                    af[i] = *(const half8*)(As + m * 64 + (g ^ (m & 7)) * 8);
                }
#pragma unroll
                for (int j = 0; j < WNT; ++j) {
                    int n = wn + j * 16 + l15;
                    bf[j] = *(const half8*)(Bs + n * 64 + (g ^ (n & 7)) * 8);
                }
#pragma unroll
                for (int i = 0; i < WMT; ++i)
#pragma unroll
                    for (int j = 0; j < WNT; ++j)
                        acc[i][j] = __builtin_amdgcn_mfma_f32_16x16x32_f16(
                            af[i], bf[j], acc[i][j], 0, 0, 0);
            }
        }
#pragma unroll
        for (int i = 0; i < WMT; ++i)
#pragma unroll
            for (int j = 0; j < WNT; ++j)
#pragma unroll
                for (int r = 0; r < 4; ++r) {
                    size_t row = m0 + wm + i * 16 + quad * 4 + r;
                    size_t col = n0 + wn + j * 16 + l15;
                    ((float*)Cout)[row * N + col] = acc[i][j][r];
                }
        return;
    }

    for (int k0 = 0; k0 < K; k0 += 64) {
        __syncthreads();
#pragma unroll
        for (int i = 0; i < BM * 8 / 256; ++i) {
            int chunk = i * 256 + tid;
            int row = chunk >> 3, c = chunk & 7;
            int gc = c ^ (row & 7);
            async16(A + (size_t)(m0 + row) * K + k0 + gc * 8, As + chunk * 8);
        }
#pragma unroll
        for (int i = 0; i < BN * 8 / 256; ++i) {
            int chunk = i * 256 + tid;
            int row = chunk >> 3, c = chunk & 7;
            int gc = c ^ (row & 7);
            async16(B + (size_t)(n0 + row) * K + k0 + gc * 8, Bs + chunk * 8);
        }
        __syncthreads();
#pragma unroll
        for (int ks = 0; ks < 2; ++ks) {
            const int g = ks * 4 + quad;
            half8 af[WMT], bf[WNT];
#pragma unroll
            for (int i = 0; i < WMT; ++i) {
                int m = wm + i * 16 + l15;
                af[i] = *(const half8*)(As + m * 64 + (g ^ (m & 7)) * 8);
            }
#pragma unroll
            for (int j = 0; j < WNT; ++j) {
                int n = wn + j * 16 + l15;
                bf[j] = *(const half8*)(Bs + n * 64 + (g ^ (n & 7)) * 8);
            }
#pragma unroll
            for (int i = 0; i < WMT; ++i)
#pragma unroll
                for (int j = 0; j < WNT; ++j)
                    acc[i][j] = __builtin_amdgcn_mfma_f32_16x16x32_f16(af[i], bf[j],
                                                                       acc[i][j], 0, 0, 0);
        }
    }

    if (MODE == 2) {
        // Stage masked f16 output in LDS (vt path: transposed + key-perm on
        // write), then stream out coalesced b128 rows.
        __syncthreads();                  // all waves done reading As/Bs
        const bool isV = (n0 >= 2 * INNER);
#pragma unroll
        for (int i = 0; i < WMT; ++i) {
            int row0 = m0 + wm + i * 16 + quad * 4;
            float4 mv = *(const float4*)(mask + row0);
            float mvr[4] = {mv.x, mv.y, mv.z, mv.w};
#pragma unroll
            for (int j = 0; j < WNT; ++j) {
                int col = wn + j * 16 + l15;          // local col 0..127
#pragma unroll
                for (int r = 0; r < 4; ++r) {
                    half_t hv = (half_t)(acc[i][j][r] * mvr[r]);
                    int rl = wm + i * 16 + quad * 4 + r;   // local row 0..127
                    if (isV) {
                        // perm within 32-seq blocks: g=(rl>>2)&7 -> (g&3)<<1|g>>2
                        int g = (rl >> 2) & 7;
                        int sp = (rl & ~31) | ((((g & 3) << 1) | (g >> 2)) << 2) |
                                 (rl & 3);
                        Sh[col * 136 + sp] = hv;      // [d-col][seq-perm]
                    } else {
                        Sh[rl * 136 + col] = hv;      // [seq][col]
                    }
                }
            }
        }
        __syncthreads();
        if (isV) {
            const int vb = n0 - 2 * INNER;            // multiple of 128
            const int bb = m0 >> 11;
            const int seq0 = m0 & (SEQ - 1);
#pragma unroll
            for (int it = 0; it < 8; ++it) {
                int lin = it * 256 + tid;
                int dl = lin >> 4, ch = lin & 15;
                half8 v = *(const half8*)(Sh + dl * 136 + ch * 8);
                int vc = vb + dl;
                *(half8*)(vt + ((size_t)(bb * 16 + (vc >> 6)) * DH + (vc & 63)) * SEQ +
                          seq0 + ch * 8) = v;
            }
        } else {
#pragma unroll
            for (int it = 0; it < 8; ++it) {
                int lin = it * 256 + tid;
                int rl = lin >> 4, ch = lin & 15;
                half8 v = *(const half8*)(Sh + rl * 136 + ch * 8);
                *(half8*)((half_t*)Cout + (size_t)(m0 + rl) * 2048 + n0 + ch * 8) = v;
            }
        }
        return;
    }

#pragma unroll
    for (int i = 0; i < WMT; ++i)
#pragma unroll
        for (int j = 0; j < WNT; ++j)
#pragma unroll
            for (int r = 0; r < 4; ++r) {
                size_t row = m0 + wm + i * 16 + quad * 4 + r;
                size_t col = n0 + wn + j * 16 + l15;
                ((float*)Cout)[row * N + col] = acc[i][j][r];
            }
}

// ------------------------------ attention ----------------------------------
// R11 structure: 512 thr = 8 waves; 256 q/block (32/wave); 2-way key split.
// Double-buffered 64-key K/V tiles (32 KB LDS), ONE __syncthreads per tile,
// prefetch right after barrier. P never touches LDS (vt key permutation).
// l accumulated on the matrix pipe: accL = mfma(pf, ones, accL).
__global__ __launch_bounds__(512, 4) void attn_mfma(const half_t* __restrict__ qk,
                                                    const half_t* __restrict__ vt,
                                                    half_t* __restrict__ O0,
                                                    half_t* __restrict__ O1,
                                                    float* __restrict__ l_ws) {
    __shared__ half_t Ks[2][64 * 64];     // [key][d], chunks xor-swizzled (16 KB)
    __shared__ half_t Vs[2][64 * 64];     // [d][key-perm], xor-swizzled  (16 KB)

    const int tid = threadIdx.x;
    const int wave = tid >> 6;
    const int lane = tid & 63;
    const int l15 = lane & 15;
    const int quad = lane >> 4;
    const int sw = l15 & 7;
    const int bh = blockIdx.y;
    const int b = bh >> 4, h = bh & 15;
    const int qi0 = blockIdx.x * 256;
    const int kh = blockIdx.z;            // keys [kh*1024, kh*1024+1024)

    // Q fragments from global (0.125*log2e folded into W_qkv q-cols)
    const half_t* qrow0 = qk + (size_t)(b * SEQ + qi0 + wave * 32 + l15) * 2048 + h * DH;
    const half_t* qrow1 = qrow0 + (size_t)16 * 2048;
    half8 qf[2][2];
    qf[0][0] = *(const half8*)(qrow0 + quad * 8);
    qf[0][1] = *(const half8*)(qrow0 + 32 + quad * 8);
    qf[1][0] = *(const half8*)(qrow1 + quad * 8);
    qf[1][1] = *(const half8*)(qrow1 + 32 + quad * 8);

    const half_t* kbase0 = qk + (size_t)b * SEQ * 2048 + INNER + h * DH;
    const half_t* vtb = vt + (size_t)bh * DH * SEQ;

    half8 vone;                           // B = 1 fragment for l-MFMA
#pragma unroll
    for (int j = 0; j < 8; ++j) vone[j] = (half_t)1.0f;

    floatx4 accO[2][4];
#pragma unroll
    for (int hh = 0; hh < 2; ++hh)
#pragma unroll
        for (int nt = 0; nt < 4; ++nt) accO[hh][nt] = (floatx4){0.f, 0.f, 0.f, 0.f};
    floatx4 accL[2] = {(floatx4){0.f, 0.f, 0.f, 0.f}, (floatx4){0.f, 0.f, 0.f, 0.f}};

    auto stage = [&](int kt, int buf) {
        const int kjg = kh * 1024 + kt * 64;
        int row = tid >> 3, c = tid & 7;
        int gc = c ^ (row & 7);
        async16(kbase0 + (size_t)(kjg + row) * 2048 + gc * 8, Ks[buf] + tid * 8);
        async16(vtb + (size_t)row * SEQ + kjg + gc * 8, Vs[buf] + tid * 8);
    };

    stage(0, 0);

    for (int kt = 0; kt < 16; ++kt) {
        const int buf = kt & 1;
        __syncthreads();                  // buf's loads drained; buf^1 reads done
        if (kt + 1 < 16) stage(kt + 1, buf ^ 1);   // ages a full tile

        // ---- S^T = K Q^T : rows = keys (mt*16+quad*4+r), cols = q (l15) ----
        floatx4 accS[2][4];
#pragma unroll
        for (int hh = 0; hh < 2; ++hh)
#pragma unroll
            for (int mt = 0; mt < 4; ++mt) accS[hh][mt] = (floatx4){0.f, 0.f, 0.f, 0.f};
        __builtin_amdgcn_s_setprio(1);
#pragma unroll
        for (int ks = 0; ks < 2; ++ks) {
#pragma unroll
            for (int mt = 0; mt < 4; ++mt) {
                half8 af = *(const half8*)(Ks[buf] + (mt * 16 + l15) * 64 +
                                           ((ks * 4 + quad) ^ sw) * 8);
                accS[0][mt] = __builtin_amdgcn_mfma_f32_16x16x32_f16(af, qf[0][ks],
                                                                     accS[0][mt], 0, 0, 0);
                accS[1][mt] = __builtin_amdgcn_mfma_f32_16x16x32_f16(af, qf[1][ks],
                                                                     accS[1][mt], 0, 0, 0);
            }
        }
        __builtin_amdgcn_s_setprio(0);

        // ---- p = 2^s, packed in-register as the PV A-fragment ----
        half8 pf[2][2];                   // [hh][c]: keys c*32 + quad*8 + j
#pragma unroll
        for (int hh = 0; hh < 2; ++hh)
#pragma unroll
            for (int c = 0; c < 2; ++c) {
                half8 p8;
#pragma unroll
                for (int mtl = 0; mtl < 2; ++mtl)
#pragma unroll
                    for (int r = 0; r < 4; ++r)
                        p8[mtl * 4 + r] =
                            (half_t)__builtin_amdgcn_exp2f(accS[hh][c * 2 + mtl][r]);
                pf[hh][c] = p8;
            }

        // ---- PV + l: vf b128 chunk == A-slot key order (vt pre-permuted) ----
        __builtin_amdgcn_s_setprio(1);
#pragma unroll
        for (int c = 0; c < 2; ++c) {
            const int ko = ((c * 4 + quad) ^ sw) * 8;
            accL[0] = __builtin_amdgcn_mfma_f32_16x16x32_f16(pf[0][c], vone,
                                                             accL[0], 0, 0, 0);
            accL[1] = __builtin_amdgcn_mfma_f32_16x16x32_f16(pf[1][c], vone,
                                                             accL[1], 0, 0, 0);
#pragma unroll
            for (int nt = 0; nt < 4; ++nt) {
                half8 vf = *(const half8*)(Vs[buf] + (nt * 16 + l15) * 64 + ko);
                accO[0][nt] = __builtin_amdgcn_mfma_f32_16x16x32_f16(pf[0][c], vf,
                                                                     accO[0][nt], 0, 0, 0);
                accO[1][nt] = __builtin_amdgcn_mfma_f32_16x16x32_f16(pf[1][c], vf,
                                                                     accO[1][nt], 0, 0, 0);
            }
        }
        __builtin_amdgcn_s_setprio(0);
    }

    // l: accL[hh][r] = Sum_k p for q = hh*16 + quad*4 + r (all l15 identical)
    float* lw = l_ws + (size_t)kh * 65536 + (size_t)bh * SEQ + qi0 + wave * 32;
    if (l15 == 0) {
#pragma unroll
        for (int hh = 0; hh < 2; ++hh)
#pragma unroll
            for (int r = 0; r < 4; ++r)
                lw[hh * 16 + quad * 4 + r] = accL[hh][r];
    }

    half_t* obuf = (kh == 0) ? O0 : O1;
#pragma unroll
    for (int hh = 0; hh < 2; ++hh)
#pragma unroll
        for (int nt = 0; nt < 4; ++nt)
#pragma unroll
            for (int r = 0; r < 4; ++r) {
                size_t row = (size_t)(b * SEQ + qi0 + wave * 32 + hh * 16 + quad * 4 + r);
                obuf[row * INNER + h * DH + nt * 16 + l15] = (half_t)accO[hh][nt][r];
            }
}

// ------------------------------- launch ------------------------------------
extern "C" void kernel_launch(void* const* d_in, const int* in_sizes, int n_in,
                              void* d_out, int out_size, void* d_ws, size_t ws_size,
                              hipStream_t stream) {
    const float* x    = (const float*)d_in[0];
    const float* mask = (const float*)d_in[1];
    const float* Wqkv = (const float*)d_in[2];   // [1024][3072]
    const float* Wout = (const float*)d_in[3];   // [1024][1024]
    float* out = (float*)d_out;

    half_t* x_h    = (half_t*)d_ws;                       // also O0 after g1
    half_t* Wqkv_t = x_h + (size_t)4 * 1024 * 1024;
    half_t* Wout_t = Wqkv_t + (size_t)3 * 1024 * 1024;
    half_t* qk     = Wout_t + (size_t)1024 * 1024;        // [4096][2048]
    half_t* vt     = qk + (size_t)8 * 1024 * 1024;        // [32][64][2048]
    half_t* aout_h = vt + (size_t)4 * 1024 * 1024;        // [4096][1024] = O1
    float*  l_ws   = (float*)(aout_h + (size_t)4 * 1024 * 1024);  // 2*65536 + 2
    half_t* O0     = x_h;

    prep<<<6146, 256, 0, stream>>>(x, Wqkv, Wout, mask, x_h, Wqkv_t, Wout_t,
                                   l_ws + 131072);

    gemm_f16_bt<2, 4, 4><<<dim3(3 * INNER / 128, BROWS / 128), 256, 0, stream>>>(
        x_h, Wqkv_t, qk, vt, mask, nullptr, BROWS, 3 * INNER, DIM);

    attn_mfma<<<dim3(SEQ / 256, 2 * NH, 2), 512, 0, stream>>>(
        qk, vt, O0, aout_h, l_ws);

    // fused combine+GEMM: A = (O0 + O1) * inv, out = A @ Wout^T
    gemm_f16_bt<3, 2, 4><<<dim3(DIM / 128, BROWS / 64), 256, 0, stream>>>(
        O0, Wout_t, out, aout_h, mask, l_ws, BROWS, DIM, INNER);
}

// Round 8
// 169.368 us; speedup vs baseline: 1.0431x; 1.0180x over previous
//
#include <hip/hip_runtime.h>

// ---------------------------------------------------------------------------
// Attention_25151328485403 — f16 MFMA path, round 17
//   prep:  converts (x->f16; W_qkv -> [N][K] q-cols ×0.125*log2e; W_out) +
//          per-batch masked-key counts
//   g1  :  qkv = x_h @ Wqkv^T, rows ×mask[row]; q,k -> qk [row][2048];
//          V -> vt [bh][64 d][2048 seq-permuted]; LDS-staged coalesced
//          epilogue stores; XCD swizzle.
//   at  :  64 q/wave (512 q/block, 8 waves), 2-way key split, grid 256 =
//          exactly 1 block/CU. Per-CU per kt: staging 16 KB (was 32),
//          LDS reads 128 b128 (was 256) — af/vf each serve 4 hh. P fully
//          in-register; l via MFMA×ones. VGPR ~200, 2 waves/SIMD.
//   g2  :  MODE 3 fused combine+GEMM (A = (O0+O1)*inv), XCD swizzle.
// Lessons: R9/R10 Ps LDS round-trip was serial chain. R12 vmcnt ring NEUTRAL.
// R13 128-key + 1-block/CU(4-wave) gemm2 REGRESSED. R15 16q/wave REGRESSED
// (2x traffic beats occupancy). R16 epilogue scatter fix NEUTRAL. R17: the
// mirror of R15 — traffic & LDS-BW halve, occupancy drops to 8 waves/CU;
// per-kt cycle model says traffic/LDS were the binding terms (2050+3200 cy
// of 6450), occupancy was not (R11==R12).
// ---------------------------------------------------------------------------

typedef _Float16 half_t;
typedef __attribute__((ext_vector_type(8))) _Float16 half8;
typedef __attribute__((ext_vector_type(4))) _Float16 half4;
typedef __attribute__((ext_vector_type(4))) float floatx4;

#define SEQ 2048
#define DIM 1024
#define INNER 1024
#define NH 16
#define DH 64
#define BROWS 4096

__device__ inline void async16(const half_t* g, half_t* l) {
    __builtin_amdgcn_global_load_lds(
        (const __attribute__((address_space(1))) void*)g,
        (__attribute__((address_space(3))) void*)l, 16, 0, 0);
}

// ------------------- fused prep (converts + mask counts) -------------------
__global__ __launch_bounds__(256) void prep(const float* __restrict__ x,
                                            const float* __restrict__ Wqkv,
                                            const float* __restrict__ Wout,
                                            const float* __restrict__ mask,
                                            half_t* __restrict__ x_h,
                                            half_t* __restrict__ Wqkv_t,
                                            half_t* __restrict__ Wout_t,
                                            float* __restrict__ mc) {
    __shared__ float tile[32][33];
    const int bid = blockIdx.x;
    const int tid = threadIdx.x;

    if (bid < 2048) {
        int i = (bid * 256 + tid) * 8;
        float4 v0 = *(const float4*)(x + i);
        float4 v1 = *(const float4*)(x + i + 4);
        half_t h[8];
        h[0] = (half_t)v0.x; h[1] = (half_t)v0.y; h[2] = (half_t)v0.z; h[3] = (half_t)v0.w;
        h[4] = (half_t)v1.x; h[5] = (half_t)v1.y; h[6] = (half_t)v1.z; h[7] = (half_t)v1.w;
        *(half8*)(x_h + i) = *(half8*)h;
        return;
    }
    if (bid >= 6144) {                        // masked-key count for batch b
        int b = bid - 6144;
        float4 a = ((const float4*)(mask + (size_t)b * SEQ))[tid * 2];
        float4 c = ((const float4*)(mask + (size_t)b * SEQ))[tid * 2 + 1];
        float s = a.x + a.y + a.z + a.w + c.x + c.y + c.z + c.w;
#pragma unroll
        for (int off = 1; off < 64; off <<= 1) s += __shfl_xor(s, off, 64);
        float* red = &tile[0][0];
        if ((tid & 63) == 0) red[tid >> 6] = s;
        __syncthreads();
        if (tid == 0) mc[b] = (float)SEQ - (red[0] + red[1] + red[2] + red[3]);
        return;
    }

    const float* in;
    half_t* out;
    int R, C, scaleRows, c0, r0;
    float scale;
    if (bid < 5120) {
        int idx = bid - 2048;                 // W_qkv: 96 x 32 tiles
        in = Wqkv; out = Wqkv_t; R = DIM; C = 3 * INNER;
        scaleRows = INNER; scale = 0.1803368801111f;   // 0.125 * log2(e)
        c0 = (idx % 96) * 32; r0 = (idx / 96) * 32;
    } else {
        int idx = bid - 5120;                 // W_out: 32 x 32 tiles
        in = Wout; out = Wout_t; R = INNER; C = DIM;
        scaleRows = 0; scale = 1.0f;
        c0 = (idx % 32) * 32; r0 = (idx / 32) * 32;
    }
    const int tx = tid & 31, ty = tid >> 5;
#pragma unroll
    for (int i = 0; i < 32; i += 8)
        tile[ty + i][tx] = in[(size_t)(r0 + ty + i) * C + c0 + tx];
    __syncthreads();
#pragma unroll
    for (int i = 0; i < 32; i += 8) {
        int oc = c0 + ty + i;
        float s = (oc < scaleRows) ? scale : 1.0f;
        out[(size_t)oc * R + r0 + tx] = (half_t)(tile[tx][ty + i] * s);
    }
}

// ------------------------------ mfma GEMM ----------------------------------
// MODE 0: f32 C[M,N].
// MODE 2: qkv — rows scaled by mask[row]; q/k -> qk [row][2048] f16 and
//         V -> vt [bh][64][2048 perm], both via LDS-staged coalesced stores.
// MODE 3: fused combine+GEMM: A-staging = (A + A1)[row][k] * inv[row][h].
// All modes: XCD-aware block swizzle (8 | gridDim.x*gridDim.y).
template <int MODE, int WMT, int WNT>
__global__ __launch_bounds__(256) void gemm_f16_bt(const half_t* __restrict__ A,
                                                   const half_t* __restrict__ B,
                                                   void* __restrict__ Cout,
                                                   half_t* __restrict__ vt,
                                                   const float* __restrict__ mask,
                                                   const float* __restrict__ lws,
                                                   int M, int N, int K) {
    constexpr int BM = 32 * WMT;
    constexpr int BN = 32 * WNT;
    constexpr int ABSZ = BM * 64 + BN * 64;
    constexpr int SHSZ = (MODE == 2 && ABSZ < 128 * 136) ? 128 * 136 : ABSZ;
    __shared__ half_t Sh[SHSZ];
    half_t* As = Sh;
    half_t* Bs = Sh + BM * 64;
    const int tid = threadIdx.x;
    const int wave = tid >> 6;
    const int lane = tid & 63;
    const int l15 = lane & 15;
    const int quad = lane >> 4;

    // XCD-aware swizzle: consecutive zz within an XCD share A-panels.
    const int z = blockIdx.y * gridDim.x + blockIdx.x;
    const int tot = gridDim.x * gridDim.y;
    const int zz = (z & 7) * (tot >> 3) + (z >> 3);
    const int m0 = (zz / gridDim.x) * BM;
    const int n0 = (zz % gridDim.x) * BN;
    const int wm = (wave & 1) * (16 * WMT);
    const int wn = (wave >> 1) * (16 * WNT);

    floatx4 acc[WMT][WNT];
#pragma unroll
    for (int i = 0; i < WMT; ++i)
#pragma unroll
        for (int j = 0; j < WNT; ++j) acc[i][j] = (floatx4){0.f, 0.f, 0.f, 0.f};

    if constexpr (MODE == 3) {
        static_assert(WMT == 2, "MODE 3 assumes BM=64");
        const half_t* A1 = vt;            // second input (O1)
        __shared__ float invL[64][16];
        // ---- build inv table: inv[row][h] = qmask / (l0+l1-mc) ----
        {
            int r = tid >> 2;
            int rg = m0 + r;
            int bb = rg >> 11;
            int q = rg & 2047;
            float qm = mask[rg];
            float mcv = lws[131072 + bb];
#pragma unroll
            for (int j = 0; j < 4; ++j) {
                int it = (tid & 3) * 4 + j;
                float l0 = lws[(size_t)(bb * 16 + it) * 2048 + q];
                float l1 = lws[65536 + (size_t)(bb * 16 + it) * 2048 + q];
                float l = l0 + l1 - mcv;
                invL[r][it] = (qm > 0.5f && l > 0.f) ? 1.0f / l : 0.f;
            }
        }
        // ---- preload A regs for kit 0 ----
        const int ch0 = tid, ch1 = 256 + tid;
        const int r0 = ch0 >> 3, g0 = (ch0 & 7) ^ (r0 & 7);
        const int r1 = ch1 >> 3, g1 = (ch1 & 7) ^ (r1 & 7);
        const half_t* a0p = A + (size_t)(m0 + r0) * K + g0 * 8;
        const half_t* b0p = A1 + (size_t)(m0 + r0) * K + g0 * 8;
        const half_t* a1p = A + (size_t)(m0 + r1) * K + g1 * 8;
        const half_t* b1p = A1 + (size_t)(m0 + r1) * K + g1 * 8;
        half8 aC0 = *(const half8*)(a0p);
        half8 bC0 = *(const half8*)(b0p);
        half8 aC1 = *(const half8*)(a1p);
        half8 bC1 = *(const half8*)(b1p);

        for (int kit = 0; kit < 16; ++kit) {
            const int k0 = kit * 64;
            __syncthreads();              // prev compute done; As/Bs free
            // combined, scaled A -> LDS
            {
                float iv0 = invL[r0][kit], iv1 = invL[r1][kit];
                half8 s0, s1;
#pragma unroll
                for (int j = 0; j < 8; ++j) {
                    s0[j] = (half_t)(((float)aC0[j] + (float)bC0[j]) * iv0);
                    s1[j] = (half_t)(((float)aC1[j] + (float)bC1[j]) * iv1);
                }
                *(half8*)(As + ch0 * 8) = s0;
                *(half8*)(As + ch1 * 8) = s1;
            }
            // B staging via global_load_lds
#pragma unroll
            for (int i = 0; i < BN * 8 / 256; ++i) {
                int chunk = i * 256 + tid;
                int row = chunk >> 3, c = chunk & 7;
                int gc = c ^ (row & 7);
                async16(B + (size_t)(n0 + row) * K + k0 + gc * 8, Bs + chunk * 8);
            }
            // prefetch next-iteration A regs (rides the barrier's B drain)
            if (kit + 1 < 16) {
                const int kn = k0 + 64;
                aC0 = *(const half8*)(a0p + kn);
                bC0 = *(const half8*)(b0p + kn);
                aC1 = *(const half8*)(a1p + kn);
                bC1 = *(const half8*)(b1p + kn);
            }
            __syncthreads();              // staging (LDS + vmem) drained
#pragma unroll
            for (int ks = 0; ks < 2; ++ks) {
                const int g = ks * 4 + quad;
                half8 af[WMT], bf[WNT];
#pragma unroll
                for (int i = 0; i < WMT; ++i) {
                    int m = wm + i * 16 + l15;
                    af[i] = *(const half8*)(As + m * 64 + (g ^ (m & 7)) * 8);
                }
#pragma unroll
                for (int j = 0; j < WNT; ++j) {
                    int n = wn + j * 16 + l15;
                    bf[j] = *(const half8*)(Bs + n * 64 + (g ^ (n & 7)) * 8);
                }
#pragma unroll
                for (int i = 0; i < WMT; ++i)
#pragma unroll
                    for (int j = 0; j < WNT; ++j)
                        acc[i][j] = __builtin_amdgcn_mfma_f32_16x16x32_f16(
                            af[i], bf[j], acc[i][j], 0, 0, 0);
            }
        }
#pragma unroll
        for (int i = 0; i < WMT; ++i)
#pragma unroll
            for (int j = 0; j < WNT; ++j)
#pragma unroll
                for (int r = 0; r < 4; ++r) {
                    size_t row = m0 + wm + i * 16 + quad * 4 + r;
                    size_t col = n0 + wn + j * 16 + l15;
                    ((float*)Cout)[row * N + col] = acc[i][j][r];
                }
        return;
    }

    for (int k0 = 0; k0 < K; k0 += 64) {
        __syncthreads();
#pragma unroll
        for (int i = 0; i < BM * 8 / 256; ++i) {
            int chunk = i * 256 + tid;
            int row = chunk >> 3, c = chunk & 7;
            int gc = c ^ (row & 7);
            async16(A + (size_t)(m0 + row) * K + k0 + gc * 8, As + chunk * 8);
        }
#pragma unroll
        for (int i = 0; i < BN * 8 / 256; ++i) {
            int chunk = i * 256 + tid;
            int row = chunk >> 3, c = chunk & 7;
            int gc = c ^ (row & 7);
            async16(B + (size_t)(n0 + row) * K + k0 + gc * 8, Bs + chunk * 8);
        }
        __syncthreads();
#pragma unroll
        for (int ks = 0; ks < 2; ++ks) {
            const int g = ks * 4 + quad;
            half8 af[WMT], bf[WNT];
#pragma unroll
            for (int i = 0; i < WMT; ++i) {
                int m = wm + i * 16 + l15;
                af[i] = *(const half8*)(As + m * 64 + (g ^ (m & 7)) * 8);
            }
#pragma unroll
            for (int j = 0; j < WNT; ++j) {
                int n = wn + j * 16 + l15;
                bf[j] = *(const half8*)(Bs + n * 64 + (g ^ (n & 7)) * 8);
            }
#pragma unroll
            for (int i = 0; i < WMT; ++i)
#pragma unroll
                for (int j = 0; j < WNT; ++j)
                    acc[i][j] = __builtin_amdgcn_mfma_f32_16x16x32_f16(af[i], bf[j],
                                                                       acc[i][j], 0, 0, 0);
        }
    }

    if (MODE == 2) {
        // Stage masked f16 output in LDS (vt path: transposed + key-perm on
        // write), then stream out coalesced b128 rows.
        __syncthreads();                  // all waves done reading As/Bs
        const bool isV = (n0 >= 2 * INNER);
#pragma unroll
        for (int i = 0; i < WMT; ++i) {
            int row0 = m0 + wm + i * 16 + quad * 4;
            float4 mv = *(const float4*)(mask + row0);
            float mvr[4] = {mv.x, mv.y, mv.z, mv.w};
#pragma unroll
            for (int j = 0; j < WNT; ++j) {
                int col = wn + j * 16 + l15;          // local col 0..127
#pragma unroll
                for (int r = 0; r < 4; ++r) {
                    half_t hv = (half_t)(acc[i][j][r] * mvr[r]);
                    int rl = wm + i * 16 + quad * 4 + r;   // local row 0..127
                    if (isV) {
                        // perm within 32-seq blocks: g=(rl>>2)&7 -> (g&3)<<1|g>>2
                        int g = (rl >> 2) & 7;
                        int sp = (rl & ~31) | ((((g & 3) << 1) | (g >> 2)) << 2) |
                                 (rl & 3);
                        Sh[col * 136 + sp] = hv;      // [d-col][seq-perm]
                    } else {
                        Sh[rl * 136 + col] = hv;      // [seq][col]
                    }
                }
            }
        }
        __syncthreads();
        if (isV) {
            const int vb = n0 - 2 * INNER;            // multiple of 128
            const int bb = m0 >> 11;
            const int seq0 = m0 & (SEQ - 1);
#pragma unroll
            for (int it = 0; it < 8; ++it) {
                int lin = it * 256 + tid;
                int dl = lin >> 4, ch = lin & 15;
                half8 v = *(const half8*)(Sh + dl * 136 + ch * 8);
                int vc = vb + dl;
                *(half8*)(vt + ((size_t)(bb * 16 + (vc >> 6)) * DH + (vc & 63)) * SEQ +
                          seq0 + ch * 8) = v;
            }
        } else {
#pragma unroll
            for (int it = 0; it < 8; ++it) {
                int lin = it * 256 + tid;
                int rl = lin >> 4, ch = lin & 15;
                half8 v = *(const half8*)(Sh + rl * 136 + ch * 8);
                *(half8*)((half_t*)Cout + (size_t)(m0 + rl) * 2048 + n0 + ch * 8) = v;
            }
        }
        return;
    }

#pragma unroll
    for (int i = 0; i < WMT; ++i)
#pragma unroll
        for (int j = 0; j < WNT; ++j)
#pragma unroll
            for (int r = 0; r < 4; ++r) {
                size_t row = m0 + wm + i * 16 + quad * 4 + r;
                size_t col = n0 + wn + j * 16 + l15;
                ((float*)Cout)[row * N + col] = acc[i][j][r];
            }
}

// ------------------------------ attention ----------------------------------
// 512 thr = 8 waves; 64 q/wave (512 q/block); 2-way key split. Grid
// 4 x 32 x 2 = 256 blocks = exactly 1/CU (2 waves/SIMD). Per-CU per kt:
// staging 16 KB, 128 b128 LDS reads — af/vf each feed 4 hh sub-tiles.
// Double-buffered 64-key K/V tiles (32 KB LDS), ONE __syncthreads per
// tile. P in-register (vt key permutation); l via MFMA×ones.
__global__ __launch_bounds__(512, 2) void attn_mfma(const half_t* __restrict__ qk,
                                                    const half_t* __restrict__ vt,
                                                    half_t* __restrict__ O0,
                                                    half_t* __restrict__ O1,
                                                    float* __restrict__ l_ws) {
    __shared__ half_t Ks[2][64 * 64];     // [key][d], chunks xor-swizzled (16 KB)
    __shared__ half_t Vs[2][64 * 64];     // [d][key-perm], xor-swizzled  (16 KB)

    const int tid = threadIdx.x;
    const int wave = tid >> 6;
    const int lane = tid & 63;
    const int l15 = lane & 15;
    const int quad = lane >> 4;
    const int sw = l15 & 7;
    const int bh = blockIdx.y;
    const int b = bh >> 4, h = bh & 15;
    const int qi0 = blockIdx.x * 512;
    const int kh = blockIdx.z;            // keys [kh*1024, kh*1024+1024)

    // Q fragments from global (0.125*log2e folded into W_qkv q-cols)
    half8 qf[4][2];
#pragma unroll
    for (int hh = 0; hh < 4; ++hh) {
        const half_t* qrow =
            qk + (size_t)(b * SEQ + qi0 + wave * 64 + hh * 16 + l15) * 2048 + h * DH;
        qf[hh][0] = *(const half8*)(qrow + quad * 8);
        qf[hh][1] = *(const half8*)(qrow + 32 + quad * 8);
    }

    const half_t* kbase0 = qk + (size_t)b * SEQ * 2048 + INNER + h * DH;
    const half_t* vtb = vt + (size_t)bh * DH * SEQ;

    half8 vone;                           // B = 1 fragment for l-MFMA
#pragma unroll
    for (int j = 0; j < 8; ++j) vone[j] = (half_t)1.0f;

    floatx4 accO[4][4];
#pragma unroll
    for (int hh = 0; hh < 4; ++hh)
#pragma unroll
        for (int nt = 0; nt < 4; ++nt) accO[hh][nt] = (floatx4){0.f, 0.f, 0.f, 0.f};
    floatx4 accL[4];
#pragma unroll
    for (int hh = 0; hh < 4; ++hh) accL[hh] = (floatx4){0.f, 0.f, 0.f, 0.f};

    auto stage = [&](int kt, int buf) {
        const int kjg = kh * 1024 + kt * 64;
        int row = tid >> 3, c = tid & 7;
        int gc = c ^ (row & 7);
        async16(kbase0 + (size_t)(kjg + row) * 2048 + gc * 8, Ks[buf] + tid * 8);
        async16(vtb + (size_t)row * SEQ + kjg + gc * 8, Vs[buf] + tid * 8);
    };

    stage(0, 0);

    for (int kt = 0; kt < 16; ++kt) {
        const int buf = kt & 1;
        __syncthreads();                  // buf's loads drained; buf^1 reads done
        if (kt + 1 < 16) stage(kt + 1, buf ^ 1);   // ages a full tile

        // ---- S^T = K Q^T : rows = keys (mt*16+quad*4+r), cols = q (l15) ----
        // One af read serves all 4 hh sub-tiles (key lever of this round).
        floatx4 accS[4][4];
#pragma unroll
        for (int hh = 0; hh < 4; ++hh)
#pragma unroll
            for (int mt = 0; mt < 4; ++mt) accS[hh][mt] = (floatx4){0.f, 0.f, 0.f, 0.f};
        __builtin_amdgcn_s_setprio(1);
#pragma unroll
        for (int ks = 0; ks < 2; ++ks) {
#pragma unroll
            for (int mt = 0; mt < 4; ++mt) {
                half8 af = *(const half8*)(Ks[buf] + (mt * 16 + l15) * 64 +
                                           ((ks * 4 + quad) ^ sw) * 8);
#pragma unroll
                for (int hh = 0; hh < 4; ++hh)
                    accS[hh][mt] = __builtin_amdgcn_mfma_f32_16x16x32_f16(
                        af, qf[hh][ks], accS[hh][mt], 0, 0, 0);
            }
        }
        __builtin_amdgcn_s_setprio(0);

        // ---- p = 2^s, packed in-register as the PV A-fragment ----
        half8 pf[4][2];                   // [hh][c]: keys c*32 + quad*8 + j
#pragma unroll
        for (int hh = 0; hh < 4; ++hh)
#pragma unroll
            for (int c = 0; c < 2; ++c) {
                half8 p8;
#pragma unroll
                for (int mtl = 0; mtl < 2; ++mtl)
#pragma unroll
                    for (int r = 0; r < 4; ++r)
                        p8[mtl * 4 + r] =
                            (half_t)__builtin_amdgcn_exp2f(accS[hh][c * 2 + mtl][r]);
                pf[hh][c] = p8;
            }

        // ---- PV + l: one vf read serves 4 hh; vt pre-permuted key order ----
        __builtin_amdgcn_s_setprio(1);
#pragma unroll
        for (int c = 0; c < 2; ++c) {
            const int ko = ((c * 4 + quad) ^ sw) * 8;
#pragma unroll
            for (int hh = 0; hh < 4; ++hh)
                accL[hh] = __builtin_amdgcn_mfma_f32_16x16x32_f16(pf[hh][c], vone,
                                                                  accL[hh], 0, 0, 0);
#pragma unroll
            for (int nt = 0; nt < 4; ++nt) {
                half8 vf = *(const half8*)(Vs[buf] + (nt * 16 + l15) * 64 + ko);
#pragma unroll
                for (int hh = 0; hh < 4; ++hh)
                    accO[hh][nt] = __builtin_amdgcn_mfma_f32_16x16x32_f16(
                        pf[hh][c], vf, accO[hh][nt], 0, 0, 0);
            }
        }
        __builtin_amdgcn_s_setprio(0);
    }

    // l: accL[hh][r] = Sum_k p for q = wave*64 + hh*16 + quad*4 + r
    float* lw = l_ws + (size_t)kh * 65536 + (size_t)bh * SEQ + qi0 + wave * 64;
    if (l15 == 0) {
#pragma unroll
        for (int hh = 0; hh < 4; ++hh)
#pragma unroll
            for (int r = 0; r < 4; ++r)
                lw[hh * 16 + quad * 4 + r] = accL[hh][r];
    }

    half_t* obuf = (kh == 0) ? O0 : O1;
#pragma unroll
    for (int hh = 0; hh < 4; ++hh)
#pragma unroll
        for (int nt = 0; nt < 4; ++nt)
#pragma unroll
            for (int r = 0; r < 4; ++r) {
                size_t row = (size_t)(b * SEQ + qi0 + wave * 64 + hh * 16 + quad * 4 + r);
                obuf[row * INNER + h * DH + nt * 16 + l15] = (half_t)accO[hh][nt][r];
            }
}

// ------------------------------- launch ------------------------------------
extern "C" void kernel_launch(void* const* d_in, const int* in_sizes, int n_in,
                              void* d_out, int out_size, void* d_ws, size_t ws_size,
                              hipStream_t stream) {
    const float* x    = (const float*)d_in[0];
    const float* mask = (const float*)d_in[1];
    const float* Wqkv = (const float*)d_in[2];   // [1024][3072]
    const float* Wout = (const float*)d_in[3];   // [1024][1024]
    float* out = (float*)d_out;

    half_t* x_h    = (half_t*)d_ws;                       // also O0 after g1
    half_t* Wqkv_t = x_h + (size_t)4 * 1024 * 1024;
    half_t* Wout_t = Wqkv_t + (size_t)3 * 1024 * 1024;
    half_t* qk     = Wout_t + (size_t)1024 * 1024;        // [4096][2048]
    half_t* vt     = qk + (size_t)8 * 1024 * 1024;        // [32][64][2048]
    half_t* aout_h = vt + (size_t)4 * 1024 * 1024;        // [4096][1024] = O1
    float*  l_ws   = (float*)(aout_h + (size_t)4 * 1024 * 1024);  // 2*65536 + 2
    half_t* O0     = x_h;

    prep<<<6146, 256, 0, stream>>>(x, Wqkv, Wout, mask, x_h, Wqkv_t, Wout_t,
                                   l_ws + 131072);

    gemm_f16_bt<2, 4, 4><<<dim3(3 * INNER / 128, BROWS / 128), 256, 0, stream>>>(
        x_h, Wqkv_t, qk, vt, mask, nullptr, BROWS, 3 * INNER, DIM);

    attn_mfma<<<dim3(SEQ / 512, 2 * NH, 2), 512, 0, stream>>>(
        qk, vt, O0, aout_h, l_ws);

    // fused combine+GEMM: A = (O0 + O1) * inv, out = A @ Wout^T
    gemm_f16_bt<3, 2, 4><<<dim3(DIM / 128, BROWS / 64), 256, 0, stream>>>(
        O0, Wout_t, out, aout_h, mask, l_ws, BROWS, DIM, INNER);
}